// Round 6
// baseline (3427.818 us; speedup 1.0000x reference)
//
#include <hip/hip_runtime.h>
#include <hip/hip_fp16.h>

#define B_TOT 32768
#define D1 4096
#define D2 2048
#define D3 1024
#define NCLS 19

typedef _Float16 f16;
typedef __attribute__((ext_vector_type(8))) _Float16 f16x8;
typedef __attribute__((ext_vector_type(4))) float f32x4;
typedef __attribute__((ext_vector_type(16))) float f32x16;

// ---------------- helpers ----------------

__device__ __forceinline__ void gl_lds16(void* ldsDst, const void* gSrc) {
  __builtin_amdgcn_global_load_lds(
      (__attribute__((address_space(1))) void*)(void*)(gSrc),
      (__attribute__((address_space(3))) void*)(ldsDst),
      16, 0, 0);
}

__device__ __forceinline__ float gelu_f(float x) {
  return 0.5f * x * (1.0f + erff(x * 0.70710678118654752f));
}

// v ~= (float)h + (float)l * (1/4096)
__device__ __forceinline__ void mk_pair(float v, f16& h, f16& l) {
  f16 hh = (f16)v;
  h = hh;
  l = (f16)((v - (float)hh) * 4096.0f);
}

#define FENCE asm volatile("" ::: "memory")
#define BARRIER { FENCE; __builtin_amdgcn_s_barrier(); FENCE; }
#define WAITV6 asm volatile("s_waitcnt vmcnt(6)" ::: "memory")
#define WAITV4 asm volatile("s_waitcnt vmcnt(4)" ::: "memory")
#define WAITV0 asm volatile("s_waitcnt vmcnt(0)" ::: "memory")

// ---------------- prep kernels ----------------

// Out: Th/Tl [N][K] = split of gam[k]*W[k][n]  (gam==nullptr -> 1)
__global__ void transpose_pair_kernel(const float* __restrict__ W,
                                      const float* __restrict__ gam,
                                      f16* __restrict__ Th, f16* __restrict__ Tl,
                                      int K, int N) {
  __shared__ float t[64][65];
  int k0 = blockIdx.y * 64, n0 = blockIdx.x * 64;
  int tx = threadIdx.x & 63, ty = threadIdx.x >> 6;
#pragma unroll
  for (int i = 0; i < 16; ++i) {
    int kl = ty + i * 4;
    int kk = k0 + kl;
    if (kk < K) {
      float s = gam ? gam[kk] : 1.0f;
      t[kl][tx] = s * W[(size_t)kk * N + n0 + tx];
    }
  }
  __syncthreads();
#pragma unroll
  for (int i = 0; i < 16; ++i) {
    int nl = ty + i * 4;
    int kk = k0 + tx;
    if (kk < K) {
      float v = t[tx][nl];
      f16 h, l; mk_pair(v, h, l);
      size_t o = (size_t)(n0 + nl) * K + kk;
      Th[o] = h; Tl[o] = l;
    }
  }
}

// split-K partials for u/v
#define UV_KCHUNK 64
__global__ void uv_part_kernel(const float* __restrict__ W, const float* __restrict__ gam,
                               const float* __restrict__ bet,
                               float* __restrict__ up, float* __restrict__ vp,
                               int K, int N) {
  int n = blockIdx.x * 256 + threadIdx.x;
  int c = blockIdx.y;
  if (n >= N) return;
  int kb = c * UV_KCHUNK;
  int ke = kb + UV_KCHUNK; if (ke > K) ke = K;
  float su = 0.f, sv = 0.f;
  for (int k = kb; k < ke; ++k) {
    float w = W[(size_t)k * N + n];
    su += gam[k] * w;
    sv += bet[k] * w;
  }
  up[(size_t)c * N + n] = su;
  vp[(size_t)c * N + n] = sv;
}

__global__ void uv_reduce_kernel(const float* __restrict__ up, const float* __restrict__ vp,
                                 float* __restrict__ u, float* __restrict__ v,
                                 int N, int nc) {
  int n = blockIdx.x * 256 + threadIdx.x;
  if (n >= N) return;
  float su = 0.f, sv = 0.f;
  for (int c = 0; c < nc; ++c) {
    su += up[(size_t)c * N + n];
    sv += vp[(size_t)c * N + n];
  }
  u[n] = su; v[n] = sv;
}

__global__ void pair_kernel(const float* __restrict__ x, f16* __restrict__ h,
                            f16* __restrict__ l, int n) {
  int i = blockIdx.x * 256 + threadIdx.x;
  if (i < n) {
    f16 hh, ll; mk_pair(x[i], hh, ll);
    h[i] = hh; l[i] = ll;
  }
}

// ---------------- stats ----------------

__global__ void stats_kernel(const float* __restrict__ ps, const float* __restrict__ pq,
                             int np_, float invN, float* __restrict__ m,
                             float* __restrict__ rs, int rows) {
  int r = blockIdx.x * 256 + threadIdx.x;
  if (r >= rows) return;
  float s = 0.f, q = 0.f;
  for (int p = 0; p < np_; ++p) {
    s += ps[(size_t)r * np_ + p];
    q += pq[(size_t)r * np_ + p];
  }
  float mean = s * invN;
  float var = q * invN - mean * mean;
  m[r] = mean;
  rs[r] = 1.0f / sqrtf(var + 1e-5f);
}

// ---------------- layer-1 GEMM (K=32 + one-hot gathers) — round-3 proven ----------------

template <int MODE>
__global__ __launch_bounds__(256, 2)
void gemm_split(const f16* __restrict__ Ah, const f16* __restrict__ Al,
                const f16* __restrict__ Bh, const f16* __restrict__ Bl,
                int K, int N,
                const float* __restrict__ bias,
                const float* __restrict__ uvec, const float* __restrict__ vvec,
                const float* __restrict__ mrow, const float* __restrict__ rsrow,
                const int* __restrict__ c0, const int* __restrict__ c1,
                const int* __restrict__ c2, const float* __restrict__ W1raw,
                float* __restrict__ part_s, float* __restrict__ part_q, int nparts,
                f16* __restrict__ Gh, f16* __restrict__ Gl) {
  __shared__ __align__(16) f16 AhS[2][128 * 32];
  __shared__ __align__(16) f16 AlS[2][128 * 32];
  __shared__ __align__(16) f16 BhS[2][128 * 32];
  __shared__ __align__(16) f16 BlS[2][128 * 32];

  const int tid = threadIdx.x;
  const int wave = tid >> 6, lane = tid & 63;
  const int wr = wave >> 1, wc = wave & 1;
  const int lq = lane >> 4, lr = lane & 15;

  const int gx = gridDim.x;
  const int nwg = gx * gridDim.y;
  const int flat = blockIdx.y * gx + blockIdx.x;
  const int cpx = nwg >> 3;
  const int swz = (flat & 7) * cpx + (flat >> 3);
  const int bx = swz % gx, by = swz / gx;
  const int m0 = by * 128, n0 = bx * 128;

  f32x4 acc0[4][4], acc1[4][4];
  const f32x4 vz = {0.f, 0.f, 0.f, 0.f};
#pragma unroll
  for (int a = 0; a < 4; ++a)
#pragma unroll
    for (int b = 0; b < 4; ++b) { acc0[a][b] = vz; acc1[a][b] = vz; }

  const int nkt = K >> 5;

#define STAGE_TILE(buf, kt_)                                                  \
  {                                                                           \
    const int k0_ = (kt_) << 5;                                               \
    _Pragma("unroll")                                                         \
    for (int i = 0; i < 2; ++i) {                                             \
      int idx = i * 256 + tid;                                                \
      int rr = idx >> 2, kq = idx & 3;                                        \
      int kqg = kq ^ ((rr >> 1) & 3);                                         \
      size_t goffA = (size_t)(m0 + rr) * K + k0_ + kqg * 8;                   \
      size_t goffB = (size_t)(n0 + rr) * K + k0_ + kqg * 8;                   \
      gl_lds16(&AhS[buf][idx * 8], Ah + goffA);                               \
      gl_lds16(&AlS[buf][idx * 8], Al + goffA);                               \
      gl_lds16(&BhS[buf][idx * 8], Bh + goffB);                               \
      gl_lds16(&BlS[buf][idx * 8], Bl + goffB);                               \
    }                                                                         \
  }

  STAGE_TILE(0, 0);
  __syncthreads();

  for (int kt = 0; kt < nkt; ++kt) {
    const int cur = kt & 1;
    if (kt + 1 < nkt) STAGE_TILE(cur ^ 1, kt + 1);

    f16x8 af[4], alf[4], bf[4], blf[4];
#pragma unroll
    for (int mf = 0; mf < 4; ++mf) {
      int row = wr * 64 + mf * 16 + lr;
      int ca = lq ^ ((row >> 1) & 3);
      af[mf]  = *(const f16x8*)(&AhS[cur][row * 32 + ca * 8]);
      alf[mf] = *(const f16x8*)(&AlS[cur][row * 32 + ca * 8]);
    }
#pragma unroll
    for (int nf = 0; nf < 4; ++nf) {
      int col = wc * 64 + nf * 16 + lr;
      int cb = lq ^ ((col >> 1) & 3);
      bf[nf]  = *(const f16x8*)(&BhS[cur][col * 32 + cb * 8]);
      blf[nf] = *(const f16x8*)(&BlS[cur][col * 32 + cb * 8]);
    }
#pragma unroll
    for (int mf = 0; mf < 4; ++mf)
#pragma unroll
      for (int nf = 0; nf < 4; ++nf) {
        acc0[mf][nf] = __builtin_amdgcn_mfma_f32_16x16x32_f16(af[mf], bf[nf], acc0[mf][nf], 0, 0, 0);
        acc1[mf][nf] = __builtin_amdgcn_mfma_f32_16x16x32_f16(af[mf], blf[nf], acc1[mf][nf], 0, 0, 0);
        acc1[mf][nf] = __builtin_amdgcn_mfma_f32_16x16x32_f16(alf[mf], bf[nf], acc1[mf][nf], 0, 0, 0);
      }
    __syncthreads();
  }
#undef STAGE_TILE

  const int pidx = bx * 2 + wc;
#pragma unroll
  for (int mf = 0; mf < 4; ++mf) {
#pragma unroll
    for (int j = 0; j < 4; ++j) {
      const int row = m0 + wr * 64 + mf * 16 + lq * 4 + j;
      float mA = 0.f, rsA = 1.f;
      int g0 = 0, g1i = 0, g2i = 0;
      if (MODE == 1) { mA = mrow[row]; rsA = rsrow[row]; }
      if (MODE == 0) { g0 = 32 + c0[row]; g1i = 96 + c1[row]; g2i = 224 + c2[row]; }
      float rowsum = 0.f, rowsq = 0.f;
#pragma unroll
      for (int nf = 0; nf < 4; ++nf) {
        const int col = n0 + wc * 64 + nf * 16 + lr;
        float val = acc0[mf][nf][j] + acc1[mf][nf][j] * (1.0f / 4096.0f);
        float pre;
        if (MODE == 0) {
          pre = val + bias[col]
              + W1raw[(size_t)g0 * D1 + col]
              + W1raw[(size_t)g1i * D1 + col]
              + W1raw[(size_t)g2i * D1 + col];
        } else {
          pre = rsA * val - rsA * mA * uvec[col] + vvec[col] + bias[col];
        }
        float g = gelu_f(pre);
        f16 h, l; mk_pair(g, h, l);
        size_t o = (size_t)row * N + col;
        Gh[o] = h; Gl[o] = l;
        rowsum += g; rowsq += g * g;
      }
#pragma unroll
      for (int off = 1; off < 16; off <<= 1) {
        rowsum += __shfl_xor(rowsum, off);
        rowsq  += __shfl_xor(rowsq, off);
      }
      if (lr == 0) {
        part_s[(size_t)row * nparts + pidx] = rowsum;
        part_q[(size_t)row * nparts + pidx] = rowsq;
      }
    }
  }
}

// ---------------- pipelined split-f16 GEMM, 32x32x16 fragments (layers 2/3) ----------------
// BM = 128*MT, BN = 128, BK = 32; 512 threads = 8 waves (4 row x 2 col).
// Per-wave output: (32*MT) x 64 = MT x 2 tiles of 32x32. Round-4-proven schedule:
// triple-buffered LDS ring, 2-tile-ahead global_load_lds prefetch, counted
// vmcnt at iter entry (never 0 mid-loop), per-phase barrier before each
// setprio-wrapped MFMA cluster. 32x32x16 MFMA: ~25% better FLOP/cycle than
// 16x16x32 (m119: 2495 vs 2176 TF) and half the instruction count.
// A-frag: row=lane&31, k-chunk 8*(lane>>5); C/D: col=lane&31,
// row=(reg&3)+8*(reg>>2)+4*(lane>>5)  [m74/m101 verified mapping].

template <int MT>
__global__ __launch_bounds__(512, 2)
void gemm_ln(const f16* __restrict__ Ah, const f16* __restrict__ Al,
             const f16* __restrict__ Bh, const f16* __restrict__ Bl,
             int K, int N,
             const float* __restrict__ bias,
             const float* __restrict__ uvec, const float* __restrict__ vvec,
             const float* __restrict__ mrow, const float* __restrict__ rsrow,
             float* __restrict__ part_s, float* __restrict__ part_q, int nparts,
             f16* __restrict__ Gh, f16* __restrict__ Gl) {
  constexpr int BM = 128 * MT;
  __shared__ __align__(16) f16 AhS[3][BM * 32];
  __shared__ __align__(16) f16 AlS[3][BM * 32];
  __shared__ __align__(16) f16 BhS[3][128 * 32];
  __shared__ __align__(16) f16 BlS[3][128 * 32];

  const int tid = threadIdx.x;
  const int wave = tid >> 6, lane = tid & 63;
  const int wr = wave >> 1, wc = wave & 1;
  const int lm = lane & 31, lh = lane >> 5;

  const int gx = gridDim.x;
  const int nwg = gx * gridDim.y;
  const int flat = blockIdx.y * gx + blockIdx.x;
  const int cpx = nwg >> 3;
  const int swz = (flat & 7) * cpx + (flat >> 3);
  const int bx = swz % gx, by = swz / gx;
  const int m0 = by * BM, n0 = bx * 128;

  f32x16 acc0[MT][2], acc1[MT][2];
#pragma unroll
  for (int a = 0; a < MT; ++a)
#pragma unroll
    for (int b = 0; b < 2; ++b) {
#pragma unroll
      for (int e = 0; e < 16; ++e) { acc0[a][b][e] = 0.f; acc1[a][b][e] = 0.f; }
    }

  const int nkt = K >> 5;

  // A chunks per stage: BM*32/8/512 = MT; B: 1.
  auto stage0 = [&](int b, int kt_) {
    const int k0_ = kt_ << 5;
#pragma unroll
    for (int r = 0; r < MT; ++r) {
      int idx = r * 512 + tid, rr = idx >> 2, kq = idx & 3;
      int kqg = kq ^ ((rr >> 1) & 3);
      gl_lds16(&AhS[b][idx * 8], Ah + (size_t)(m0 + rr) * K + k0_ + kqg * 8);
    }
    { int rr = tid >> 2, kq = tid & 3, kqg = kq ^ ((rr >> 1) & 3);
      gl_lds16(&BhS[b][tid * 8], Bh + (size_t)(n0 + rr) * K + k0_ + kqg * 8); }
  };
  auto stage1 = [&](int b, int kt_) {
    const int k0_ = kt_ << 5;
#pragma unroll
    for (int r = 0; r < MT; ++r) {
      int idx = r * 512 + tid, rr = idx >> 2, kq = idx & 3;
      int kqg = kq ^ ((rr >> 1) & 3);
      gl_lds16(&AlS[b][idx * 8], Al + (size_t)(m0 + rr) * K + k0_ + kqg * 8);
    }
    { int rr = tid >> 2, kq = tid & 3, kqg = kq ^ ((rr >> 1) & 3);
      gl_lds16(&BlS[b][tid * 8], Bl + (size_t)(n0 + rr) * K + k0_ + kqg * 8); }
  };

  // prologue: tiles 0 and 1 in flight
  stage0(0, 0); stage1(0, 0);
  if (nkt > 1) { stage0(1, 1); stage1(1, 1); }

  for (int t = 0; t < nkt; ++t) {
    const int cb = t % 3;              // compute buffer
    const int sb = (t + 2) % 3;        // stage target (== buffer of t-1)
    // entry: drain tile t's loads; leave tile t+1's in flight (T4)
    if (t + 1 < nkt) {
      if constexpr (MT == 2) { WAITV6; } else { WAITV4; }
    } else {
      WAITV0;
    }
    BARRIER;

    const bool pf = (t + 2 < nkt);

    // B fragments for the whole iter: 2 col-tiles x 2 k-frags
    f16x8 bh[2][2], bl[2][2];
#pragma unroll
    for (int nt = 0; nt < 2; ++nt)
#pragma unroll
      for (int kf = 0; kf < 2; ++kf) {
        int col = wc * 64 + nt * 32 + lm;
        int cc = (kf * 2 + lh) ^ ((col >> 1) & 3);
        bh[nt][kf] = *(const f16x8*)(&BhS[cb][col * 32 + cc * 8]);
        bl[nt][kf] = *(const f16x8*)(&BlS[cb][col * 32 + cc * 8]);
      }
    if (pf) { stage0(sb, t + 2); if (MT == 1) stage1(sb, t + 2); }

#pragma unroll
    for (int mt = 0; mt < MT; ++mt) {
      int row = wr * (32 * MT) + mt * 32 + lm;
      f16x8 ah[2], al[2];
#pragma unroll
      for (int kf = 0; kf < 2; ++kf) {
        int ca = (kf * 2 + lh) ^ ((row >> 1) & 3);
        ah[kf] = *(const f16x8*)(&AhS[cb][row * 32 + ca * 8]);
        al[kf] = *(const f16x8*)(&AlS[cb][row * 32 + ca * 8]);
      }
      if (pf && MT == 2 && mt == 1) stage1(sb, t + 2);
      BARRIER;
      __builtin_amdgcn_s_setprio(1);
#pragma unroll
      for (int nt = 0; nt < 2; ++nt)
#pragma unroll
        for (int kf = 0; kf < 2; ++kf) {
          acc0[mt][nt] = __builtin_amdgcn_mfma_f32_32x32x16_f16(ah[kf], bh[nt][kf], acc0[mt][nt], 0, 0, 0);
          acc1[mt][nt] = __builtin_amdgcn_mfma_f32_32x32x16_f16(ah[kf], bl[nt][kf], acc1[mt][nt], 0, 0, 0);
          acc1[mt][nt] = __builtin_amdgcn_mfma_f32_32x32x16_f16(al[kf], bh[nt][kf], acc1[mt][nt], 0, 0, 0);
        }
      __builtin_amdgcn_s_setprio(0);
    }
  }

  // ---- epilogue: LN fold + gelu + split store + row partials ----
  const int pidx = bx * 2 + wc;
#pragma unroll
  for (int mt = 0; mt < MT; ++mt) {
#pragma unroll
    for (int reg = 0; reg < 16; ++reg) {
      const int rowoff = (reg & 3) + 8 * (reg >> 2) + 4 * lh;
      const int row = m0 + wr * (32 * MT) + mt * 32 + rowoff;
      const float mA = mrow[row], rsA = rsrow[row];
      float rowsum = 0.f, rowsq = 0.f;
#pragma unroll
      for (int nt = 0; nt < 2; ++nt) {
        const int col = n0 + wc * 64 + nt * 32 + lm;
        float val = acc0[mt][nt][reg] + acc1[mt][nt][reg] * (1.0f / 4096.0f);
        float pre = rsA * val - rsA * mA * uvec[col] + vvec[col] + bias[col];
        float g = gelu_f(pre);
        f16 h, l; mk_pair(g, h, l);
        size_t o = (size_t)row * N + col;
        Gh[o] = h; Gl[o] = l;
        rowsum += g; rowsq += g * g;
      }
#pragma unroll
      for (int off = 1; off < 32; off <<= 1) {
        rowsum += __shfl_xor(rowsum, off);
        rowsq  += __shfl_xor(rowsq, off);
      }
      if (lm == 0) {
        part_s[(size_t)row * nparts + pidx] = rowsum;
        part_q[(size_t)row * nparts + pidx] = rowsq;
      }
    }
  }
}

// ---------------- head: LN3 fold + W4 + mask + softmax + argmax ----------------

__global__ __launch_bounds__(256)
void head_kernel(const f16* __restrict__ gh, const f16* __restrict__ gl,
                 const float* __restrict__ m3, const float* __restrict__ rs3,
                 const float* __restrict__ gam, const float* __restrict__ bet,
                 const float* __restrict__ W4, const float* __restrict__ b4,
                 const int* __restrict__ pid, const float* __restrict__ amask,
                 float* __restrict__ out_ml, float* __restrict__ out_p,
                 float* __restrict__ out_pred, int rows) {
  const int wave = threadIdx.x >> 6, lane = threadIdx.x & 63;
  const int r = blockIdx.x * 4 + wave;
  if (r >= rows) return;
  const f16* ghr = gh + (size_t)r * D3;
  const f16* glr = gl + (size_t)r * D3;
  const float m = m3[r], rs = rs3[r];
  float acc[NCLS];
#pragma unroll
  for (int c = 0; c < NCLS; ++c) acc[c] = 0.f;
  for (int k = lane; k < D3; k += 64) {
    float g = (float)ghr[k] + (float)glr[k] * (1.0f / 4096.0f);
    float h2 = (g - m) * rs * gam[k] + bet[k];
    const float* w = W4 + (size_t)k * NCLS;
#pragma unroll
    for (int c = 0; c < NCLS; ++c) acc[c] += h2 * w[c];
  }
  for (int off = 1; off < 64; off <<= 1) {
#pragma unroll
    for (int c = 0; c < NCLS; ++c) acc[c] += __shfl_xor(acc[c], off);
  }
  const int p = pid[r];
  float ml[NCLS], mx = -3.4e38f;
#pragma unroll
  for (int c = 0; c < NCLS; ++c) {
    ml[c] = acc[c] + b4[c] + amask[(size_t)p * NCLS + c];
    mx = fmaxf(mx, ml[c]);
  }
  float ex[NCLS], s = 0.f;
#pragma unroll
  for (int c = 0; c < NCLS; ++c) { ex[c] = expf(ml[c] - mx); s += ex[c]; }
  const float inv = 1.0f / s;
  float pr[NCLS];
#pragma unroll
  for (int c = 0; c < NCLS; ++c) pr[c] = ex[c] * inv;
  int best = 0; float bp = pr[0];
#pragma unroll
  for (int c = 1; c < NCLS; ++c) { if (pr[c] > bp) { bp = pr[c]; best = c; } }
  if (lane < NCLS) {
    out_ml[(size_t)r * NCLS + lane] = ml[lane];
    out_p [(size_t)r * NCLS + lane] = pr[lane];
  }
  if (lane == 0) out_pred[r] = (float)best;
}

// ---------------- host ----------------

extern "C" void kernel_launch(void* const* d_in, const int* in_sizes, int n_in,
                              void* d_out, int out_size, void* d_ws, size_t ws_size,
                              hipStream_t stream) {
  const float* numeric = (const float*)d_in[0];
  const int*   cat0 = (const int*)d_in[1];
  const int*   cat1 = (const int*)d_in[2];
  const int*   cat2 = (const int*)d_in[3];
  const int*   pid  = (const int*)d_in[4];
  const float* amask= (const float*)d_in[5];
  const float* W1 = (const float*)d_in[6];
  const float* b1 = (const float*)d_in[7];
  const float* g1v= (const float*)d_in[8];
  const float* be1= (const float*)d_in[9];
  const float* W2 = (const float*)d_in[10];
  const float* b2 = (const float*)d_in[11];
  const float* g2v= (const float*)d_in[12];
  const float* be2= (const float*)d_in[13];
  const float* W3 = (const float*)d_in[14];
  const float* b3 = (const float*)d_in[15];
  const float* g3v= (const float*)d_in[16];
  const float* be3= (const float*)d_in[17];
  const float* W4 = (const float*)d_in[18];
  const float* b4 = (const float*)d_in[19];
  (void)in_sizes; (void)n_in; (void)out_size;

  char* p = (char*)d_ws;
  auto alloc = [&](size_t bytes) -> char* {
    char* r = p;
    p += (bytes + 255) & ~(size_t)255;
    return r;
  };

  // fixed workspace
  f16* W1t_h = (f16*)alloc((size_t)D1 * 32 * 2);
  f16* W1t_l = (f16*)alloc((size_t)D1 * 32 * 2);
  f16* W2t_h = (f16*)alloc((size_t)D2 * D1 * 2);
  f16* W2t_l = (f16*)alloc((size_t)D2 * D1 * 2);
  f16* W3t_h = (f16*)alloc((size_t)D3 * D2 * 2);
  f16* W3t_l = (f16*)alloc((size_t)D3 * D2 * 2);
  f16* An_h  = (f16*)alloc((size_t)B_TOT * 32 * 2);
  f16* An_l  = (f16*)alloc((size_t)B_TOT * 32 * 2);
  float* u2  = (float*)alloc((size_t)D2 * 4);
  float* v2  = (float*)alloc((size_t)D2 * 4);
  float* u3  = (float*)alloc((size_t)D3 * 4);
  float* v3  = (float*)alloc((size_t)D3 * 4);
  float* up_ws = (float*)alloc((size_t)64 * D2 * 4);
  float* vp_ws = (float*)alloc((size_t)64 * D2 * 4);
  float* m1  = (float*)alloc((size_t)B_TOT * 4);
  float* rs1 = (float*)alloc((size_t)B_TOT * 4);
  float* m2  = (float*)alloc((size_t)B_TOT * 4);
  float* rs2 = (float*)alloc((size_t)B_TOT * 4);
  float* m3  = (float*)alloc((size_t)B_TOT * 4);
  float* rs3 = (float*)alloc((size_t)B_TOT * 4);
  float* ps1 = (float*)alloc((size_t)B_TOT * 64 * 4);
  float* pq1 = (float*)alloc((size_t)B_TOT * 64 * 4);
  float* ps2 = (float*)alloc((size_t)B_TOT * 32 * 4);
  float* pq2 = (float*)alloc((size_t)B_TOT * 32 * 4);
  float* ps3 = (float*)alloc((size_t)B_TOT * 16 * 4);
  float* pq3 = (float*)alloc((size_t)B_TOT * 16 * 4);

  size_t fixed = (size_t)(p - (char*)d_ws);
  const size_t per_row = 2ULL * D1 * 2 + 2ULL * D2 * 2 + 2ULL * D3 * 2;  // 28672 B
  int R = B_TOT;
  while (R > 1024 && fixed + (size_t)R * per_row + 4096 > ws_size) R >>= 1;

  f16* G1h = (f16*)alloc((size_t)R * D1 * 2);
  f16* G1l = (f16*)alloc((size_t)R * D1 * 2);
  f16* G2h = (f16*)alloc((size_t)R * D2 * 2);
  f16* G2l = (f16*)alloc((size_t)R * D2 * 2);
  f16* G3h = (f16*)alloc((size_t)R * D3 * 2);
  f16* G3l = (f16*)alloc((size_t)R * D3 * 2);

  float* out_ml = (float*)d_out;
  float* out_p  = out_ml + (size_t)B_TOT * NCLS;
  float* out_pr = out_p + (size_t)B_TOT * NCLS;

  // ---- prep (once per launch) ----
  hipLaunchKernelGGL(transpose_pair_kernel, dim3(D1 / 64, 1), dim3(256), 0, stream,
                     W1, (const float*)nullptr, W1t_h, W1t_l, 32, D1);
  hipLaunchKernelGGL(transpose_pair_kernel, dim3(D2 / 64, D1 / 64), dim3(256), 0, stream,
                     W2, g1v, W2t_h, W2t_l, D1, D2);
  hipLaunchKernelGGL(transpose_pair_kernel, dim3(D3 / 64, D2 / 64), dim3(256), 0, stream,
                     W3, g2v, W3t_h, W3t_l, D2, D3);
  hipLaunchKernelGGL(uv_part_kernel, dim3(D2 / 256, D1 / UV_KCHUNK), dim3(256), 0, stream,
                     W2, g1v, be1, up_ws, vp_ws, D1, D2);
  hipLaunchKernelGGL(uv_reduce_kernel, dim3(D2 / 256), dim3(256), 0, stream,
                     up_ws, vp_ws, u2, v2, D2, D1 / UV_KCHUNK);
  hipLaunchKernelGGL(uv_part_kernel, dim3(D3 / 256, D2 / UV_KCHUNK), dim3(256), 0, stream,
                     W3, g2v, be2, up_ws, vp_ws, D2, D3);
  hipLaunchKernelGGL(uv_reduce_kernel, dim3(D3 / 256), dim3(256), 0, stream,
                     up_ws, vp_ws, u3, v3, D3, D2 / UV_KCHUNK);
  hipLaunchKernelGGL(pair_kernel, dim3((B_TOT * 32) / 256), dim3(256), 0, stream,
                     numeric, An_h, An_l, B_TOT * 32);

  for (int r0 = 0; r0 < B_TOT; r0 += R) {
    // layer 1: K=32 numeric GEMM + one-hot gathers
    hipLaunchKernelGGL((gemm_split<0>), dim3(D1 / 128, R / 128), dim3(256), 0, stream,
                       An_h + (size_t)r0 * 32, An_l + (size_t)r0 * 32, W1t_h, W1t_l,
                       32, D1, b1,
                       (const float*)nullptr, (const float*)nullptr,
                       (const float*)nullptr, (const float*)nullptr,
                       cat0 + r0, cat1 + r0, cat2 + r0, W1,
                       ps1 + (size_t)r0 * 64, pq1 + (size_t)r0 * 64, 64, G1h, G1l);
    hipLaunchKernelGGL(stats_kernel, dim3(R / 256), dim3(256), 0, stream,
                       ps1 + (size_t)r0 * 64, pq1 + (size_t)r0 * 64, 64, 1.0f / D1,
                       m1 + r0, rs1 + r0, R);
    // layer 2: pipelined 32x32, LN1 folded (BM=256)
    hipLaunchKernelGGL((gemm_ln<2>), dim3(D2 / 128, R / 256), dim3(512), 0, stream,
                       G1h, G1l, W2t_h, W2t_l, D1, D2, b2, u2, v2, m1 + r0, rs1 + r0,
                       ps2 + (size_t)r0 * 32, pq2 + (size_t)r0 * 32, 32, G2h, G2l);
    hipLaunchKernelGGL(stats_kernel, dim3(R / 256), dim3(256), 0, stream,
                       ps2 + (size_t)r0 * 32, pq2 + (size_t)r0 * 32, 32, 1.0f / D2,
                       m2 + r0, rs2 + r0, R);
    // layer 3: pipelined 32x32, LN2 folded (BM=128)
    hipLaunchKernelGGL((gemm_ln<1>), dim3(D3 / 128, R / 128), dim3(512), 0, stream,
                       G2h, G2l, W3t_h, W3t_l, D2, D3, b3, u3, v3, m2 + r0, rs2 + r0,
                       ps3 + (size_t)r0 * 16, pq3 + (size_t)r0 * 16, 16, G3h, G3l);
    hipLaunchKernelGGL(stats_kernel, dim3(R / 256), dim3(256), 0, stream,
                       ps3 + (size_t)r0 * 16, pq3 + (size_t)r0 * 16, 16, 1.0f / D3,
                       m3 + r0, rs3 + r0, R);
    // head
    hipLaunchKernelGGL(head_kernel, dim3(R / 4), dim3(256), 0, stream,
                       G3h, G3l, m3 + r0, rs3 + r0, g3v, be3, W4, b4,
                       pid + r0, amask,
                       out_ml + (size_t)r0 * NCLS, out_p + (size_t)r0 * NCLS,
                       out_pr + r0, R);
  }
}

// Round 7
// 2774.530 us; speedup vs baseline: 1.2355x; 1.2355x over previous
//
#include <hip/hip_runtime.h>
#include <hip/hip_fp16.h>

#define B_TOT 32768
#define D1 4096
#define D2 2048
#define D3 1024
#define NCLS 19

typedef _Float16 f16;
typedef __attribute__((ext_vector_type(8))) _Float16 f16x8;
typedef __attribute__((ext_vector_type(4))) float f32x4;

// ---------------- helpers ----------------

__device__ __forceinline__ void gl_lds16(void* ldsDst, const void* gSrc) {
  __builtin_amdgcn_global_load_lds(
      (__attribute__((address_space(1))) void*)(void*)(gSrc),
      (__attribute__((address_space(3))) void*)(ldsDst),
      16, 0, 0);
}

__device__ __forceinline__ float gelu_f(float x) {
  return 0.5f * x * (1.0f + erff(x * 0.70710678118654752f));
}

// v ~= (float)h + (float)l * (1/4096)
__device__ __forceinline__ void mk_pair(float v, f16& h, f16& l) {
  f16 hh = (f16)v;
  h = hh;
  l = (f16)((v - (float)hh) * 4096.0f);
}

#define FENCE asm volatile("" ::: "memory")
#define BARRIER { FENCE; __builtin_amdgcn_s_barrier(); FENCE; }
#define WAITV6 asm volatile("s_waitcnt vmcnt(6)" ::: "memory")
#define WAITV4 asm volatile("s_waitcnt vmcnt(4)" ::: "memory")
#define WAITV0 asm volatile("s_waitcnt vmcnt(0)" ::: "memory")

// ---------------- prep kernels ----------------

// Out: Th/Tl [N][K] = split of gam[k]*W[k][n]  (gam==nullptr -> 1)
__global__ void transpose_pair_kernel(const float* __restrict__ W,
                                      const float* __restrict__ gam,
                                      f16* __restrict__ Th, f16* __restrict__ Tl,
                                      int K, int N) {
  __shared__ float t[64][65];
  int k0 = blockIdx.y * 64, n0 = blockIdx.x * 64;
  int tx = threadIdx.x & 63, ty = threadIdx.x >> 6;
#pragma unroll
  for (int i = 0; i < 16; ++i) {
    int kl = ty + i * 4;
    int kk = k0 + kl;
    if (kk < K) {
      float s = gam ? gam[kk] : 1.0f;
      t[kl][tx] = s * W[(size_t)kk * N + n0 + tx];
    }
  }
  __syncthreads();
#pragma unroll
  for (int i = 0; i < 16; ++i) {
    int nl = ty + i * 4;
    int kk = k0 + tx;
    if (kk < K) {
      float v = t[tx][nl];
      f16 h, l; mk_pair(v, h, l);
      size_t o = (size_t)(n0 + nl) * K + kk;
      Th[o] = h; Tl[o] = l;
    }
  }
}

// split-K partials for u/v
#define UV_KCHUNK 64
__global__ void uv_part_kernel(const float* __restrict__ W, const float* __restrict__ gam,
                               const float* __restrict__ bet,
                               float* __restrict__ up, float* __restrict__ vp,
                               int K, int N) {
  int n = blockIdx.x * 256 + threadIdx.x;
  int c = blockIdx.y;
  if (n >= N) return;
  int kb = c * UV_KCHUNK;
  int ke = kb + UV_KCHUNK; if (ke > K) ke = K;
  float su = 0.f, sv = 0.f;
  for (int k = kb; k < ke; ++k) {
    float w = W[(size_t)k * N + n];
    su += gam[k] * w;
    sv += bet[k] * w;
  }
  up[(size_t)c * N + n] = su;
  vp[(size_t)c * N + n] = sv;
}

__global__ void uv_reduce_kernel(const float* __restrict__ up, const float* __restrict__ vp,
                                 float* __restrict__ u, float* __restrict__ v,
                                 int N, int nc) {
  int n = blockIdx.x * 256 + threadIdx.x;
  if (n >= N) return;
  float su = 0.f, sv = 0.f;
  for (int c = 0; c < nc; ++c) {
    su += up[(size_t)c * N + n];
    sv += vp[(size_t)c * N + n];
  }
  u[n] = su; v[n] = sv;
}

__global__ void pair_kernel(const float* __restrict__ x, f16* __restrict__ h,
                            f16* __restrict__ l, int n) {
  int i = blockIdx.x * 256 + threadIdx.x;
  if (i < n) {
    f16 hh, ll; mk_pair(x[i], hh, ll);
    h[i] = hh; l[i] = ll;
  }
}

// ---------------- layer-1 GEMM (K=32 + one-hot gathers) — round-3 proven ----------------

template <int MODE>
__global__ __launch_bounds__(256, 2)
void gemm_split(const f16* __restrict__ Ah, const f16* __restrict__ Al,
                const f16* __restrict__ Bh, const f16* __restrict__ Bl,
                int K, int N,
                const float* __restrict__ bias,
                const float* __restrict__ uvec, const float* __restrict__ vvec,
                const float* __restrict__ mrow, const float* __restrict__ rsrow,
                const int* __restrict__ c0, const int* __restrict__ c1,
                const int* __restrict__ c2, const float* __restrict__ W1raw,
                float* __restrict__ part_s, float* __restrict__ part_q, int nparts,
                f16* __restrict__ Gh, f16* __restrict__ Gl) {
  __shared__ __align__(16) f16 AhS[2][128 * 32];
  __shared__ __align__(16) f16 AlS[2][128 * 32];
  __shared__ __align__(16) f16 BhS[2][128 * 32];
  __shared__ __align__(16) f16 BlS[2][128 * 32];

  const int tid = threadIdx.x;
  const int wave = tid >> 6, lane = tid & 63;
  const int wr = wave >> 1, wc = wave & 1;
  const int lq = lane >> 4, lr = lane & 15;

  const int gx = gridDim.x;
  const int nwg = gx * gridDim.y;
  const int flat = blockIdx.y * gx + blockIdx.x;
  const int cpx = nwg >> 3;
  const int swz = (flat & 7) * cpx + (flat >> 3);
  const int bx = swz % gx, by = swz / gx;
  const int m0 = by * 128, n0 = bx * 128;

  f32x4 acc0[4][4], acc1[4][4];
  const f32x4 vz = {0.f, 0.f, 0.f, 0.f};
#pragma unroll
  for (int a = 0; a < 4; ++a)
#pragma unroll
    for (int b = 0; b < 4; ++b) { acc0[a][b] = vz; acc1[a][b] = vz; }

  const int nkt = K >> 5;

#define STAGE_TILE(buf, kt_)                                                  \
  {                                                                           \
    const int k0_ = (kt_) << 5;                                               \
    _Pragma("unroll")                                                         \
    for (int i = 0; i < 2; ++i) {                                             \
      int idx = i * 256 + tid;                                                \
      int rr = idx >> 2, kq = idx & 3;                                        \
      int kqg = kq ^ ((rr >> 1) & 3);                                         \
      size_t goffA = (size_t)(m0 + rr) * K + k0_ + kqg * 8;                   \
      size_t goffB = (size_t)(n0 + rr) * K + k0_ + kqg * 8;                   \
      gl_lds16(&AhS[buf][idx * 8], Ah + goffA);                               \
      gl_lds16(&AlS[buf][idx * 8], Al + goffA);                               \
      gl_lds16(&BhS[buf][idx * 8], Bh + goffB);                               \
      gl_lds16(&BlS[buf][idx * 8], Bl + goffB);                               \
    }                                                                         \
  }

  STAGE_TILE(0, 0);
  __syncthreads();

  for (int kt = 0; kt < nkt; ++kt) {
    const int cur = kt & 1;
    if (kt + 1 < nkt) STAGE_TILE(cur ^ 1, kt + 1);

    f16x8 af[4], alf[4], bf[4], blf[4];
#pragma unroll
    for (int mf = 0; mf < 4; ++mf) {
      int row = wr * 64 + mf * 16 + lr;
      int ca = lq ^ ((row >> 1) & 3);
      af[mf]  = *(const f16x8*)(&AhS[cur][row * 32 + ca * 8]);
      alf[mf] = *(const f16x8*)(&AlS[cur][row * 32 + ca * 8]);
    }
#pragma unroll
    for (int nf = 0; nf < 4; ++nf) {
      int col = wc * 64 + nf * 16 + lr;
      int cb = lq ^ ((col >> 1) & 3);
      bf[nf]  = *(const f16x8*)(&BhS[cur][col * 32 + cb * 8]);
      blf[nf] = *(const f16x8*)(&BlS[cur][col * 32 + cb * 8]);
    }
#pragma unroll
    for (int mf = 0; mf < 4; ++mf)
#pragma unroll
      for (int nf = 0; nf < 4; ++nf) {
        acc0[mf][nf] = __builtin_amdgcn_mfma_f32_16x16x32_f16(af[mf], bf[nf], acc0[mf][nf], 0, 0, 0);
        acc1[mf][nf] = __builtin_amdgcn_mfma_f32_16x16x32_f16(af[mf], blf[nf], acc1[mf][nf], 0, 0, 0);
        acc1[mf][nf] = __builtin_amdgcn_mfma_f32_16x16x32_f16(alf[mf], bf[nf], acc1[mf][nf], 0, 0, 0);
      }
    __syncthreads();
  }
#undef STAGE_TILE

  const int pidx = bx * 2 + wc;
#pragma unroll
  for (int mf = 0; mf < 4; ++mf) {
#pragma unroll
    for (int j = 0; j < 4; ++j) {
      const int row = m0 + wr * 64 + mf * 16 + lq * 4 + j;
      float mA = 0.f, rsA = 1.f;
      int g0 = 0, g1i = 0, g2i = 0;
      if (MODE == 1) { mA = mrow[row]; rsA = rsrow[row]; }
      if (MODE == 0) { g0 = 32 + c0[row]; g1i = 96 + c1[row]; g2i = 224 + c2[row]; }
      float rowsum = 0.f, rowsq = 0.f;
#pragma unroll
      for (int nf = 0; nf < 4; ++nf) {
        const int col = n0 + wc * 64 + nf * 16 + lr;
        float val = acc0[mf][nf][j] + acc1[mf][nf][j] * (1.0f / 4096.0f);
        float pre;
        if (MODE == 0) {
          pre = val + bias[col]
              + W1raw[(size_t)g0 * D1 + col]
              + W1raw[(size_t)g1i * D1 + col]
              + W1raw[(size_t)g2i * D1 + col];
        } else {
          pre = rsA * val - rsA * mA * uvec[col] + vvec[col] + bias[col];
        }
        float g = gelu_f(pre);
        f16 h, l; mk_pair(g, h, l);
        size_t o = (size_t)row * N + col;
        Gh[o] = h; Gl[o] = l;
        rowsum += g; rowsq += g * g;
      }
#pragma unroll
      for (int off = 1; off < 16; off <<= 1) {
        rowsum += __shfl_xor(rowsum, off);
        rowsq  += __shfl_xor(rowsq, off);
      }
      if (lr == 0) {
        part_s[(size_t)row * nparts + pidx] = rowsum;
        part_q[(size_t)row * nparts + pidx] = rowsq;
      }
    }
  }
}

// ---------------- pipelined split-f16 GEMM (layers 2/3) — round-4 proven core ----------------
// BM = WM*64, BN = 128, BK = 32; 512 threads = 8 waves (4 row x 2 col),
// per-wave output WM*16 x 64. Triple-buffered LDS ring, 2-tile-ahead
// prefetch via global_load_lds, counted vmcnt at iter entry (never 0
// mid-loop), per-phase barrier before each setprio-wrapped MFMA cluster.
// NEW (r7): LN stats (m, rs) computed IN-KERNEL from the producer's
// partial sums (ps/pq) into LDS — removes the separate stats_kernel
// launches. Deterministic: fixed serial per-row reduction order.

template <int WM>
__global__ __launch_bounds__(512, 2)
void gemm_ln(const f16* __restrict__ Ah, const f16* __restrict__ Al,
             const f16* __restrict__ Bh, const f16* __restrict__ Bl,
             int K, int N,
             const float* __restrict__ bias,
             const float* __restrict__ uvec, const float* __restrict__ vvec,
             const float* __restrict__ ps_in, const float* __restrict__ pq_in,
             int np_, float invN,
             float* __restrict__ part_s, float* __restrict__ part_q, int nparts,
             f16* __restrict__ Gh, f16* __restrict__ Gl) {
  constexpr int BM = WM * 64;
  __shared__ __align__(16) f16 AhS[3][BM * 32];
  __shared__ __align__(16) f16 AlS[3][BM * 32];
  __shared__ __align__(16) f16 BhS[3][128 * 32];
  __shared__ __align__(16) f16 BlS[3][128 * 32];
  __shared__ float mS[BM], rsS[BM];

  const int tid = threadIdx.x;
  const int wave = tid >> 6, lane = tid & 63;
  const int wr = wave >> 1, wc = wave & 1;
  const int lq = lane >> 4, lr = lane & 15;

  const int gx = gridDim.x;
  const int nwg = gx * gridDim.y;
  const int flat = blockIdx.y * gx + blockIdx.x;
  const int cpx = nwg >> 3;
  const int swz = (flat & 7) * cpx + (flat >> 3);
  const int bx = swz % gx, by = swz / gx;
  const int m0 = by * BM, n0 = bx * 128;

  // ---- in-kernel LN stats for this block's rows (before staging so the
  // stats loads' implicit waits don't drain the prefetch queue) ----
  for (int r = tid; r < BM; r += 512) {
    const float* pr = ps_in + (size_t)(m0 + r) * np_;
    const float* qr = pq_in + (size_t)(m0 + r) * np_;
    float s = 0.f, q = 0.f;
    for (int pp = 0; pp < np_; pp += 4) {
      float4 a = *(const float4*)(pr + pp);
      float4 b = *(const float4*)(qr + pp);
      s += a.x + a.y + a.z + a.w;
      q += b.x + b.y + b.z + b.w;
    }
    float mean = s * invN;
    mS[r] = mean;
    rsS[r] = 1.0f / sqrtf(q * invN - mean * mean + 1e-5f);
  }

  f32x4 acc0[WM][4], acc1[WM][4];
  const f32x4 vz = {0.f, 0.f, 0.f, 0.f};
#pragma unroll
  for (int a = 0; a < WM; ++a)
#pragma unroll
    for (int b = 0; b < 4; ++b) { acc0[a][b] = vz; acc1[a][b] = vz; }

  const int nkt = K >> 5;

  auto stage0 = [&](int b, int kt_) {
    const int k0_ = kt_ << 5;
#pragma unroll
    for (int r = 0; r < WM / 2; ++r) {
      int idx = r * 512 + tid, rr = idx >> 2, kq = idx & 3;
      int kqg = kq ^ ((rr >> 1) & 3);
      gl_lds16(&AhS[b][idx * 8], Ah + (size_t)(m0 + rr) * K + k0_ + kqg * 8);
    }
    { int rr = tid >> 2, kq = tid & 3, kqg = kq ^ ((rr >> 1) & 3);
      gl_lds16(&BhS[b][tid * 8], Bh + (size_t)(n0 + rr) * K + k0_ + kqg * 8); }
  };
  auto stage1 = [&](int b, int kt_) {
    const int k0_ = kt_ << 5;
#pragma unroll
    for (int r = 0; r < WM / 2; ++r) {
      int idx = r * 512 + tid, rr = idx >> 2, kq = idx & 3;
      int kqg = kq ^ ((rr >> 1) & 3);
      gl_lds16(&AlS[b][idx * 8], Al + (size_t)(m0 + rr) * K + k0_ + kqg * 8);
    }
    { int rr = tid >> 2, kq = tid & 3, kqg = kq ^ ((rr >> 1) & 3);
      gl_lds16(&BlS[b][tid * 8], Bl + (size_t)(n0 + rr) * K + k0_ + kqg * 8); }
  };

  // prologue: tiles 0 and 1 in flight
  stage0(0, 0); stage1(0, 0);
  if (nkt > 1) { stage0(1, 1); stage1(1, 1); }

  for (int t = 0; t < nkt; ++t) {
    const int cb = t % 3;              // compute buffer
    const int sb = (t + 2) % 3;        // stage target (== buffer of t-1)
    // entry: drain tile t's loads; leave tile t+1's in flight (T4)
    if (t + 1 < nkt) {
      if constexpr (WM == 4) { WAITV6; } else { WAITV4; }
    } else {
      WAITV0;
    }
    BARRIER;

    const bool pf = (t + 2 < nkt);

    f16x8 bf[4], blf[4];
#pragma unroll
    for (int ph = 0; ph < WM / 2; ++ph) {
      const int mfA = ph * 2, mfB = ph * 2 + 1;
      f16x8 aA, aAl, aB, aBl;
      {
        int rowA = wr * (WM * 16) + mfA * 16 + lr;
        int caA = lq ^ ((rowA >> 1) & 3);
        aA  = *(const f16x8*)(&AhS[cb][rowA * 32 + caA * 8]);
        aAl = *(const f16x8*)(&AlS[cb][rowA * 32 + caA * 8]);
        int rowB = wr * (WM * 16) + mfB * 16 + lr;
        int caB = lq ^ ((rowB >> 1) & 3);
        aB  = *(const f16x8*)(&AhS[cb][rowB * 32 + caB * 8]);
        aBl = *(const f16x8*)(&AlS[cb][rowB * 32 + caB * 8]);
      }
      if (ph == 0) {
#pragma unroll
        for (int nf = 0; nf < 4; ++nf) {
          int col = wc * 64 + nf * 16 + lr;
          int cc = lq ^ ((col >> 1) & 3);
          bf[nf]  = *(const f16x8*)(&BhS[cb][col * 32 + cc * 8]);
          blf[nf] = *(const f16x8*)(&BlS[cb][col * 32 + cc * 8]);
        }
      }
      if (pf) {
        if (ph == 0) { stage0(sb, t + 2); if (WM == 2) stage1(sb, t + 2); }
        if (ph == 1) stage1(sb, t + 2);
      }
      BARRIER;
      __builtin_amdgcn_s_setprio(1);
#pragma unroll
      for (int nf = 0; nf < 4; ++nf) {
        acc0[mfA][nf] = __builtin_amdgcn_mfma_f32_16x16x32_f16(aA, bf[nf], acc0[mfA][nf], 0, 0, 0);
        acc1[mfA][nf] = __builtin_amdgcn_mfma_f32_16x16x32_f16(aA, blf[nf], acc1[mfA][nf], 0, 0, 0);
        acc1[mfA][nf] = __builtin_amdgcn_mfma_f32_16x16x32_f16(aAl, bf[nf], acc1[mfA][nf], 0, 0, 0);
      }
#pragma unroll
      for (int nf = 0; nf < 4; ++nf) {
        acc0[mfB][nf] = __builtin_amdgcn_mfma_f32_16x16x32_f16(aB, bf[nf], acc0[mfB][nf], 0, 0, 0);
        acc1[mfB][nf] = __builtin_amdgcn_mfma_f32_16x16x32_f16(aB, blf[nf], acc1[mfB][nf], 0, 0, 0);
        acc1[mfB][nf] = __builtin_amdgcn_mfma_f32_16x16x32_f16(aBl, bf[nf], acc1[mfB][nf], 0, 0, 0);
      }
      __builtin_amdgcn_s_setprio(0);
    }
  }

  // ---- epilogue: LN fold + gelu + split store + row partials ----
  const int pidx = bx * 2 + wc;
#pragma unroll
  for (int mf = 0; mf < WM; ++mf) {
#pragma unroll
    for (int j = 0; j < 4; ++j) {
      const int rl = wr * (WM * 16) + mf * 16 + lq * 4 + j;
      const int row = m0 + rl;
      const float mA = mS[rl], rsA = rsS[rl];
      float rowsum = 0.f, rowsq = 0.f;
#pragma unroll
      for (int nf = 0; nf < 4; ++nf) {
        const int col = n0 + wc * 64 + nf * 16 + lr;
        float val = acc0[mf][nf][j] + acc1[mf][nf][j] * (1.0f / 4096.0f);
        float pre = rsA * val - rsA * mA * uvec[col] + vvec[col] + bias[col];
        float g = gelu_f(pre);
        f16 h, l; mk_pair(g, h, l);
        size_t o = (size_t)row * N + col;
        Gh[o] = h; Gl[o] = l;
        rowsum += g; rowsq += g * g;
      }
#pragma unroll
      for (int off = 1; off < 16; off <<= 1) {
        rowsum += __shfl_xor(rowsum, off);
        rowsq  += __shfl_xor(rowsq, off);
      }
      if (lr == 0) {
        part_s[(size_t)row * nparts + pidx] = rowsum;
        part_q[(size_t)row * nparts + pidx] = rowsq;
      }
    }
  }
}

// ---------------- head: LN3 (stats in-wave) + W4 + mask + softmax + argmax ----------------

__global__ __launch_bounds__(256)
void head_kernel(const f16* __restrict__ gh, const f16* __restrict__ gl,
                 const float* __restrict__ ps3, const float* __restrict__ pq3,
                 const float* __restrict__ gam, const float* __restrict__ bet,
                 const float* __restrict__ W4, const float* __restrict__ b4,
                 const int* __restrict__ pid, const float* __restrict__ amask,
                 float* __restrict__ out_ml, float* __restrict__ out_p,
                 float* __restrict__ out_pred, int rows) {
  const int wave = threadIdx.x >> 6, lane = threadIdx.x & 63;
  const int r = blockIdx.x * 4 + wave;
  if (r >= rows) return;
  // row stats from 16 partials (all lanes load lane&15 -> 16-group reduce)
  float s = ps3[(size_t)r * 16 + (lane & 15)];
  float q = pq3[(size_t)r * 16 + (lane & 15)];
#pragma unroll
  for (int off = 1; off < 16; off <<= 1) {
    s += __shfl_xor(s, off);
    q += __shfl_xor(q, off);
  }
  const float invN3 = 1.0f / (float)D3;
  const float m = s * invN3;
  const float rs = 1.0f / sqrtf(q * invN3 - m * m + 1e-5f);

  const f16* ghr = gh + (size_t)r * D3;
  const f16* glr = gl + (size_t)r * D3;
  float acc[NCLS];
#pragma unroll
  for (int c = 0; c < NCLS; ++c) acc[c] = 0.f;
  for (int k = lane; k < D3; k += 64) {
    float g = (float)ghr[k] + (float)glr[k] * (1.0f / 4096.0f);
    float h2 = (g - m) * rs * gam[k] + bet[k];
    const float* w = W4 + (size_t)k * NCLS;
#pragma unroll
    for (int c = 0; c < NCLS; ++c) acc[c] += h2 * w[c];
  }
  for (int off = 1; off < 64; off <<= 1) {
#pragma unroll
    for (int c = 0; c < NCLS; ++c) acc[c] += __shfl_xor(acc[c], off);
  }
  const int p = pid[r];
  float ml[NCLS], mx = -3.4e38f;
#pragma unroll
  for (int c = 0; c < NCLS; ++c) {
    ml[c] = acc[c] + b4[c] + amask[(size_t)p * NCLS + c];
    mx = fmaxf(mx, ml[c]);
  }
  float ex[NCLS], ssum = 0.f;
#pragma unroll
  for (int c = 0; c < NCLS; ++c) { ex[c] = expf(ml[c] - mx); ssum += ex[c]; }
  const float inv = 1.0f / ssum;
  float pr[NCLS];
#pragma unroll
  for (int c = 0; c < NCLS; ++c) pr[c] = ex[c] * inv;
  int best = 0; float bp = pr[0];
#pragma unroll
  for (int c = 1; c < NCLS; ++c) { if (pr[c] > bp) { bp = pr[c]; best = c; } }
  if (lane < NCLS) {
    out_ml[(size_t)r * NCLS + lane] = ml[lane];
    out_p [(size_t)r * NCLS + lane] = pr[lane];
  }
  if (lane == 0) out_pred[r] = (float)best;
}

// ---------------- host ----------------

extern "C" void kernel_launch(void* const* d_in, const int* in_sizes, int n_in,
                              void* d_out, int out_size, void* d_ws, size_t ws_size,
                              hipStream_t stream) {
  const float* numeric = (const float*)d_in[0];
  const int*   cat0 = (const int*)d_in[1];
  const int*   cat1 = (const int*)d_in[2];
  const int*   cat2 = (const int*)d_in[3];
  const int*   pid  = (const int*)d_in[4];
  const float* amask= (const float*)d_in[5];
  const float* W1 = (const float*)d_in[6];
  const float* b1 = (const float*)d_in[7];
  const float* g1v= (const float*)d_in[8];
  const float* be1= (const float*)d_in[9];
  const float* W2 = (const float*)d_in[10];
  const float* b2 = (const float*)d_in[11];
  const float* g2v= (const float*)d_in[12];
  const float* be2= (const float*)d_in[13];
  const float* W3 = (const float*)d_in[14];
  const float* b3 = (const float*)d_in[15];
  const float* g3v= (const float*)d_in[16];
  const float* be3= (const float*)d_in[17];
  const float* W4 = (const float*)d_in[18];
  const float* b4 = (const float*)d_in[19];
  (void)in_sizes; (void)n_in; (void)out_size;

  char* p = (char*)d_ws;
  auto alloc = [&](size_t bytes) -> char* {
    char* r = p;
    p += (bytes + 255) & ~(size_t)255;
    return r;
  };

  // fixed workspace
  f16* W1t_h = (f16*)alloc((size_t)D1 * 32 * 2);
  f16* W1t_l = (f16*)alloc((size_t)D1 * 32 * 2);
  f16* W2t_h = (f16*)alloc((size_t)D2 * D1 * 2);
  f16* W2t_l = (f16*)alloc((size_t)D2 * D1 * 2);
  f16* W3t_h = (f16*)alloc((size_t)D3 * D2 * 2);
  f16* W3t_l = (f16*)alloc((size_t)D3 * D2 * 2);
  f16* An_h  = (f16*)alloc((size_t)B_TOT * 32 * 2);
  f16* An_l  = (f16*)alloc((size_t)B_TOT * 32 * 2);
  float* u2  = (float*)alloc((size_t)D2 * 4);
  float* v2  = (float*)alloc((size_t)D2 * 4);
  float* u3  = (float*)alloc((size_t)D3 * 4);
  float* v3  = (float*)alloc((size_t)D3 * 4);
  float* up_ws = (float*)alloc((size_t)64 * D2 * 4);
  float* vp_ws = (float*)alloc((size_t)64 * D2 * 4);
  float* ps1 = (float*)alloc((size_t)B_TOT * 64 * 4);
  float* pq1 = (float*)alloc((size_t)B_TOT * 64 * 4);
  float* ps2 = (float*)alloc((size_t)B_TOT * 32 * 4);
  float* pq2 = (float*)alloc((size_t)B_TOT * 32 * 4);
  float* ps3 = (float*)alloc((size_t)B_TOT * 16 * 4);
  float* pq3 = (float*)alloc((size_t)B_TOT * 16 * 4);

  size_t fixed = (size_t)(p - (char*)d_ws);
  const size_t per_row = 2ULL * D1 * 2 + 2ULL * D2 * 2 + 2ULL * D3 * 2;  // 28672 B
  int R = B_TOT;
  while (R > 1024 && fixed + (size_t)R * per_row + 4096 > ws_size) R >>= 1;

  f16* G1h = (f16*)alloc((size_t)R * D1 * 2);
  f16* G1l = (f16*)alloc((size_t)R * D1 * 2);
  f16* G2h = (f16*)alloc((size_t)R * D2 * 2);
  f16* G2l = (f16*)alloc((size_t)R * D2 * 2);
  f16* G3h = (f16*)alloc((size_t)R * D3 * 2);
  f16* G3l = (f16*)alloc((size_t)R * D3 * 2);

  float* out_ml = (float*)d_out;
  float* out_p  = out_ml + (size_t)B_TOT * NCLS;
  float* out_pr = out_p + (size_t)B_TOT * NCLS;

  // ---- prep (once per launch) ----
  hipLaunchKernelGGL(transpose_pair_kernel, dim3(D1 / 64, 1), dim3(256), 0, stream,
                     W1, (const float*)nullptr, W1t_h, W1t_l, 32, D1);
  hipLaunchKernelGGL(transpose_pair_kernel, dim3(D2 / 64, D1 / 64), dim3(256), 0, stream,
                     W2, g1v, W2t_h, W2t_l, D1, D2);
  hipLaunchKernelGGL(transpose_pair_kernel, dim3(D3 / 64, D2 / 64), dim3(256), 0, stream,
                     W3, g2v, W3t_h, W3t_l, D2, D3);
  hipLaunchKernelGGL(uv_part_kernel, dim3(D2 / 256, D1 / UV_KCHUNK), dim3(256), 0, stream,
                     W2, g1v, be1, up_ws, vp_ws, D1, D2);
  hipLaunchKernelGGL(uv_reduce_kernel, dim3(D2 / 256), dim3(256), 0, stream,
                     up_ws, vp_ws, u2, v2, D2, D1 / UV_KCHUNK);
  hipLaunchKernelGGL(uv_part_kernel, dim3(D3 / 256, D2 / UV_KCHUNK), dim3(256), 0, stream,
                     W3, g2v, be2, up_ws, vp_ws, D2, D3);
  hipLaunchKernelGGL(uv_reduce_kernel, dim3(D3 / 256), dim3(256), 0, stream,
                     up_ws, vp_ws, u3, v3, D3, D2 / UV_KCHUNK);
  hipLaunchKernelGGL(pair_kernel, dim3((B_TOT * 32) / 256), dim3(256), 0, stream,
                     numeric, An_h, An_l, B_TOT * 32);

  for (int r0 = 0; r0 < B_TOT; r0 += R) {
    // layer 1: K=32 numeric GEMM + one-hot gathers
    hipLaunchKernelGGL((gemm_split<0>), dim3(D1 / 128, R / 128), dim3(256), 0, stream,
                       An_h + (size_t)r0 * 32, An_l + (size_t)r0 * 32, W1t_h, W1t_l,
                       32, D1, b1,
                       (const float*)nullptr, (const float*)nullptr,
                       (const float*)nullptr, (const float*)nullptr,
                       cat0 + r0, cat1 + r0, cat2 + r0, W1,
                       ps1 + (size_t)r0 * 64, pq1 + (size_t)r0 * 64, 64, G1h, G1l);
    // layer 2: pipelined, LN1 stats in-kernel (BM=256)
    hipLaunchKernelGGL((gemm_ln<4>), dim3(D2 / 128, R / 256), dim3(512), 0, stream,
                       G1h, G1l, W2t_h, W2t_l, D1, D2, b2, u2, v2,
                       ps1 + (size_t)r0 * 64, pq1 + (size_t)r0 * 64, 64, 1.0f / D1,
                       ps2 + (size_t)r0 * 32, pq2 + (size_t)r0 * 32, 32, G2h, G2l);
    // layer 3: pipelined, LN2 stats in-kernel (BM=128)
    hipLaunchKernelGGL((gemm_ln<2>), dim3(D3 / 128, R / 128), dim3(512), 0, stream,
                       G2h, G2l, W3t_h, W3t_l, D2, D3, b3, u3, v3,
                       ps2 + (size_t)r0 * 32, pq2 + (size_t)r0 * 32, 32, 1.0f / D2,
                       ps3 + (size_t)r0 * 16, pq3 + (size_t)r0 * 16, 16, G3h, G3l);
    // head (LN3 stats in-wave)
    hipLaunchKernelGGL(head_kernel, dim3(R / 4), dim3(256), 0, stream,
                       G3h, G3l, ps3 + (size_t)r0 * 16, pq3 + (size_t)r0 * 16,
                       g3v, be3, W4, b4,
                       pid + r0, amask,
                       out_ml + (size_t)r0 * NCLS, out_p + (size_t)r0 * NCLS,
                       out_pr + r0, R);
  }
}